// Round 3
// baseline (206.747 us; speedup 1.0000x reference)
//
#include <hip/hip_runtime.h>

#define WDIM 1920
#define HDIM 1080
#define TPB 256
#define PPB 4                 // pairs per block
#define NBLK 2048             // 8192 / PPB
#define XF4 (PPB * WDIM / 4)  // 1920 float4s per block x-region
#define YF4 (PPB * HDIM / 4)  // 1080 float4s per block y-region
#define LN2 0.69314718056f

__device__ __forceinline__ float clog1m(float p) {
    return fmaxf(__log2f(1.f - p) * LN2, -100.f);
}
__device__ __forceinline__ float clogp(float p) {
    return fmaxf(__log2f(p) * LN2, -100.f);
}

// Fused: per-block partial BCE + last-block-done final reduction.
// Ticket is zeroed by a 4-byte hipMemsetAsync each launch (ws is poisoned).
__global__ __launch_bounds__(TPB) void bce_fused(const float* __restrict__ px,
                                                 const float* __restrict__ py,
                                                 const int2* __restrict__ tgt,
                                                 float* __restrict__ partial_loss,
                                                 float* __restrict__ partial_cnt,
                                                 unsigned* __restrict__ ticket,
                                                 float* __restrict__ out) {
    const int t = threadIdx.x;
    const int blk = blockIdx.x;
    const int p0 = blk * PPB;

    // 1) Block-uniform tgt read (32 B): scalarized, never joins the vmem queue.
    const int4* tp = (const int4*)(tgt + p0);
    int4 ta = tp[0];           // pairs 0,1: (x0,y0,x1,y1)
    int4 tb = tp[1];           // pairs 2,3

    const float4* bx = (const float4*)px + (size_t)blk * XF4;
    const float4* by = (const float4*)py + (size_t)blk * YF4;
    const float4 z4 = make_float4(0.f, 0.f, 0.f, 0.f);

    // 2) issue ALL 13 streaming loads immediately (48 KB/block in flight).
    float4 vx[8];
    #pragma unroll
    for (int j = 0; j < 8; ++j) {
        int idx = t + j * TPB;
        vx[j] = (j < 7 || t < XF4 - 7 * TPB) ? bx[idx] : z4;   // pad -> q=1 -> log 0
    }
    float4 vy[5];
    #pragma unroll
    for (int j = 0; j < 5; ++j) {
        int idx = t + j * TPB;
        vy[j] = (j < 4 || t < YF4 - 4 * TPB) ? by[idx] : z4;
    }

    // 3) per-pair validity as a uniform 4-bit mask, in-register (no LDS).
    int cxa[PPB], cya[PPB];
    cxa[0] = min(max(ta.x, 0), WDIM - 1); cya[0] = min(max(ta.y, 0), HDIM - 1);
    cxa[1] = min(max(ta.z, 0), WDIM - 1); cya[1] = min(max(ta.w, 0), HDIM - 1);
    cxa[2] = min(max(tb.x, 0), WDIM - 1); cya[2] = min(max(tb.y, 0), HDIM - 1);
    cxa[3] = min(max(tb.z, 0), WDIM - 1); cya[3] = min(max(tb.w, 0), HDIM - 1);
    unsigned vmask = 0;
    #pragma unroll
    for (int p = 0; p < PPB; ++p)
        vmask |= ((cxa[p] != 0) | (cya[p] != 0)) << p;   // valid unless (0,0)

    const float cstx = -LN2 / WDIM;
    const float csty = -LN2 / HDIM;

    // 4) target-element correction gathers: issued LAST (in-order returns).
    float pt = 1.f, qt = 1.f;
    const bool corr = (t < PPB) && (((vmask >> t) & 1u) != 0u);
    if (corr) {
        int cx = (t == 0) ? cxa[0] : (t == 1) ? cxa[1] : (t == 2) ? cxa[2] : cxa[3];
        int cy = (t == 0) ? cya[0] : (t == 1) ? cya[1] : (t == 2) ? cya[2] : cya[3];
        pt = px[(size_t)(p0 + t) * WDIM + cx];
        qt = py[(size_t)(p0 + t) * HDIM + cy];
    }

    float acc = 0.f;

    // ---- x region: 1920 float4s ----
    #pragma unroll
    for (int j = 0; j < 8; ++j) {
        int idx = t + j * TPB;
        int pli = min(idx / 480, PPB - 1);   // clamp (padded tail -> pli 4)
        float4 v = vx[j];
        // min product (5.96e-8)^4 = 1.26e-29 (normal); per-element log >= -16.6
        // so the -100 clamp can never bind on this path.
        float q = (1.f - v.x) * (1.f - v.y) * (1.f - v.z) * (1.f - v.w);
        float w = (float)((vmask >> pli) & 1u) * cstx;
        acc = fmaf(w, __log2f(q), acc);
    }

    // ---- y region: 1080 float4s ----
    #pragma unroll
    for (int j = 0; j < 5; ++j) {
        int idx = t + j * TPB;
        int pli = min(idx / 270, PPB - 1);
        float4 v = vy[j];
        float q = (1.f - v.x) * (1.f - v.y) * (1.f - v.z) * (1.f - v.w);
        float w = (float)((vmask >> pli) & 1u) * csty;
        acc = fmaf(w, __log2f(q), acc);
    }

    // 5) correction consumed last
    if (corr) {
        acc += (clog1m(pt) - clogp(pt)) * (1.f / WDIM)
             + (clog1m(qt) - clogp(qt)) * (1.f / HDIM);
    }

    // block reduce: acc only — valid count is popc(vmask), uniform.
    #pragma unroll
    for (int o = 32; o > 0; o >>= 1)
        acc += __shfl_down(acc, o, 64);
    __shared__ float rs[TPB / 64], rc[TPB / 64];
    __shared__ bool amlast;
    if ((t & 63) == 0) rs[t >> 6] = acc;
    __syncthreads();
    if (t == 0) {
        partial_loss[blk] = rs[0] + rs[1] + rs[2] + rs[3];
        partial_cnt[blk]  = (float)__popc(vmask & 0xFu);
        // release: make this block's partials device-visible, then ticket++.
        __threadfence();
        unsigned old = atomicAdd(ticket, 1u);
        amlast = (old == NBLK - 1);
    }
    __syncthreads();

    if (!amlast) return;

    // ---- last-arriving block: final reduction (same order as old bce_final,
    //      bit-identical result). acquire: fence before reading partials. ----
    __threadfence();
    const float4* pl4 = (const float4*)partial_loss;
    const float4* pc4 = (const float4*)partial_cnt;
    float s = 0.f, c = 0.f;
    #pragma unroll
    for (int j = 0; j < 2; ++j) {
        float4 a = pl4[t + j * TPB];
        float4 b = pc4[t + j * TPB];
        s += (a.x + a.y) + (a.z + a.w);
        c += (b.x + b.y) + (b.z + b.w);
    }
    #pragma unroll
    for (int o = 32; o > 0; o >>= 1) {
        s += __shfl_down(s, o, 64);
        c += __shfl_down(c, o, 64);
    }
    if ((t & 63) == 0) { rs[t >> 6] = s; rc[t >> 6] = c; }
    __syncthreads();
    if (t == 0) {
        float ts = rs[0] + rs[1] + rs[2] + rs[3];
        float tc = rc[0] + rc[1] + rc[2] + rc[3];
        out[0] = ts / fmaxf(tc, 1.f);
    }
}

extern "C" void kernel_launch(void* const* d_in, const int* in_sizes, int n_in,
                              void* d_out, int out_size, void* d_ws, size_t ws_size,
                              hipStream_t stream) {
    const float* px = (const float*)d_in[0];
    const float* py = (const float*)d_in[1];
    const int2* tgt = (const int2*)d_in[2];
    float* out = (float*)d_out;

    float* pl = (float*)d_ws;
    float* pc = pl + NBLK;
    unsigned* ticket = (unsigned*)(pc + NBLK);

    // ws is poisoned each iteration -> re-zero the 4-byte ticket in-stream.
    hipMemsetAsync(ticket, 0, sizeof(unsigned), stream);
    bce_fused<<<dim3(NBLK), dim3(TPB), 0, stream>>>(px, py, tgt, pl, pc, ticket, out);
}

// Round 4
// 112.310 us; speedup vs baseline: 1.8409x; 1.8409x over previous
//
#include <hip/hip_runtime.h>

#define WDIM 1920
#define HDIM 1080
#define TPB 256
#define PPB 4                 // pairs per block
#define NBLK 2048             // 8192 / PPB
#define XF4 (PPB * WDIM / 4)  // 1920 float4s per block x-region
#define YF4 (PPB * HDIM / 4)  // 1080 float4s per block y-region
#define LN2 0.69314718056f

__device__ __forceinline__ float clog1m(float p) {
    return fmaxf(__log2f(1.f - p) * LN2, -100.f);
}
__device__ __forceinline__ float clogp(float p) {
    return fmaxf(__log2f(p) * LN2, -100.f);
}

// R3 lesson (kernel journal): do NOT fuse the final reduction via a
// last-block ticket here. Device-scope __threadfence() per block -> L2
// writeback across 8 non-coherent XCD L2s; 2048 of them + a contended
// single-line atomic serialized ~100us (bce_fused: 120us/dispatch at
// 0.02% HBM). Two-kernel structure is the right shape at this grid size.
__global__ __launch_bounds__(TPB) void bce_main(const float* __restrict__ px,
                                                const float* __restrict__ py,
                                                const int2* __restrict__ tgt,
                                                float* __restrict__ partial_loss,
                                                float* __restrict__ partial_cnt) {
    const int t = threadIdx.x;
    const int blk = blockIdx.x;
    const int p0 = blk * PPB;

    // 1) Block-uniform tgt read (32 B): scalarized, never joins the vmem queue.
    const int4* tp = (const int4*)(tgt + p0);
    int4 ta = tp[0];           // pairs 0,1: (x0,y0,x1,y1)
    int4 tb = tp[1];           // pairs 2,3

    const float4* bx = (const float4*)px + (size_t)blk * XF4;
    const float4* by = (const float4*)py + (size_t)blk * YF4;
    const float4 z4 = make_float4(0.f, 0.f, 0.f, 0.f);

    // 2) issue ALL 13 streaming loads immediately (48 KB/block in flight).
    float4 vx[8];
    #pragma unroll
    for (int j = 0; j < 8; ++j) {
        int idx = t + j * TPB;
        vx[j] = (j < 7 || t < XF4 - 7 * TPB) ? bx[idx] : z4;   // pad -> q=1 -> log 0
    }
    float4 vy[5];
    #pragma unroll
    for (int j = 0; j < 5; ++j) {
        int idx = t + j * TPB;
        vy[j] = (j < 4 || t < YF4 - 4 * TPB) ? by[idx] : z4;
    }

    // 3) per-pair validity as a uniform 4-bit mask, in-register (no LDS).
    int cxa[PPB], cya[PPB];
    cxa[0] = min(max(ta.x, 0), WDIM - 1); cya[0] = min(max(ta.y, 0), HDIM - 1);
    cxa[1] = min(max(ta.z, 0), WDIM - 1); cya[1] = min(max(ta.w, 0), HDIM - 1);
    cxa[2] = min(max(tb.x, 0), WDIM - 1); cya[2] = min(max(tb.y, 0), HDIM - 1);
    cxa[3] = min(max(tb.z, 0), WDIM - 1); cya[3] = min(max(tb.w, 0), HDIM - 1);
    unsigned vmask = 0;
    #pragma unroll
    for (int p = 0; p < PPB; ++p)
        vmask |= ((cxa[p] != 0) | (cya[p] != 0)) << p;   // valid unless (0,0)

    const float cstx = -LN2 / WDIM;   // == old wx[p] when valid (bit*cst identical)
    const float csty = -LN2 / HDIM;

    // 4) target-element correction gathers: issued LAST so they return after
    //    the streaming loads (in-order) and are consumed at the end.
    //    p can be 0/1 here -> keep clamps.
    float pt = 1.f, qt = 1.f;
    const bool corr = (t < PPB) && (((vmask >> t) & 1u) != 0u);
    if (corr) {
        int cx = (t == 0) ? cxa[0] : (t == 1) ? cxa[1] : (t == 2) ? cxa[2] : cxa[3];
        int cy = (t == 0) ? cya[0] : (t == 1) ? cya[1] : (t == 2) ? cya[2] : cya[3];
        pt = px[(size_t)(p0 + t) * WDIM + cx];
        qt = py[(size_t)(p0 + t) * HDIM + cy];
    }

    float acc = 0.f;

    // ---- x region: 1920 float4s ----
    #pragma unroll
    for (int j = 0; j < 8; ++j) {
        int idx = t + j * TPB;
        int pli = min(idx / 480, PPB - 1);   // clamp (padded tail -> pli 4)
        float4 v = vx[j];
        // min product (5.96e-8)^4 = 1.26e-29 (normal); per-element log >= -16.6
        // so the -100 clamp can never bind on this path.
        float q = (1.f - v.x) * (1.f - v.y) * (1.f - v.z) * (1.f - v.w);
        float w = (float)((vmask >> pli) & 1u) * cstx;
        acc = fmaf(w, __log2f(q), acc);
    }

    // ---- y region: 1080 float4s ----
    #pragma unroll
    for (int j = 0; j < 5; ++j) {
        int idx = t + j * TPB;
        int pli = min(idx / 270, PPB - 1);
        float4 v = vy[j];
        float q = (1.f - v.x) * (1.f - v.y) * (1.f - v.z) * (1.f - v.w);
        float w = (float)((vmask >> pli) & 1u) * csty;
        acc = fmaf(w, __log2f(q), acc);
    }

    // 5) correction consumed last (its gathers overlapped the compute above)
    if (corr) {
        acc += (clog1m(pt) - clogp(pt)) * (1.f / WDIM)
             + (clog1m(qt) - clogp(qt)) * (1.f / HDIM);
    }

    // block reduce: acc only — valid count is popc(vmask), uniform.
    #pragma unroll
    for (int o = 32; o > 0; o >>= 1)
        acc += __shfl_down(acc, o, 64);
    __shared__ float rs[TPB / 64];
    if ((t & 63) == 0) rs[t >> 6] = acc;
    __syncthreads();
    if (t == 0) {
        partial_loss[blk] = rs[0] + rs[1] + rs[2] + rs[3];
        partial_cnt[blk]  = (float)__popc(vmask & 0xFu);
    }
}

__global__ __launch_bounds__(TPB) void bce_final(const float* __restrict__ pl,
                                                 const float* __restrict__ pc,
                                                 float* __restrict__ out) {
    const int t = threadIdx.x;
    // NBLK=2048 floats per array -> 512 float4 -> 2 per thread, vectorized.
    const float4* pl4 = (const float4*)pl;
    const float4* pc4 = (const float4*)pc;
    float s = 0.f, c = 0.f;
    #pragma unroll
    for (int j = 0; j < 2; ++j) {
        float4 a = pl4[t + j * TPB];
        float4 b = pc4[t + j * TPB];
        s += (a.x + a.y) + (a.z + a.w);
        c += (b.x + b.y) + (b.z + b.w);
    }
    #pragma unroll
    for (int o = 32; o > 0; o >>= 1) {
        s += __shfl_down(s, o, 64);
        c += __shfl_down(c, o, 64);
    }
    __shared__ float rs[TPB / 64], rc[TPB / 64];
    if ((t & 63) == 0) { rs[t >> 6] = s; rc[t >> 6] = c; }
    __syncthreads();
    if (t == 0) {
        float ts = rs[0] + rs[1] + rs[2] + rs[3];
        float tc = rc[0] + rc[1] + rc[2] + rc[3];
        out[0] = ts / fmaxf(tc, 1.f);
    }
}

extern "C" void kernel_launch(void* const* d_in, const int* in_sizes, int n_in,
                              void* d_out, int out_size, void* d_ws, size_t ws_size,
                              hipStream_t stream) {
    const float* px = (const float*)d_in[0];
    const float* py = (const float*)d_in[1];
    const int2* tgt = (const int2*)d_in[2];
    float* out = (float*)d_out;

    float* pl = (float*)d_ws;
    float* pc = pl + NBLK;

    bce_main<<<dim3(NBLK), dim3(TPB), 0, stream>>>(px, py, tgt, pl, pc);
    bce_final<<<1, TPB, 0, stream>>>(pl, pc, out);
}